// Round 1
// baseline (237.720 us; speedup 1.0000x reference)
//
#include <hip/hip_runtime.h>
#include <hip/hip_bf16.h>

// out[e] = relu(concat(x[src],x[dst]) @ W1 + b1) @ W2 + b2
// Split: uv[n][0:256] = x[n]@W1[0:256], uv[n][256:512] = x[n]@W1[256:512] (bf16)
// then per-edge: sum_k relu(uv[src][k]+uv[dst][256+k]+b1[k])*W2[k] + b2.

typedef short short8 __attribute__((ext_vector_type(8)));
typedef float f32x4 __attribute__((ext_vector_type(4)));

#define DINC 256
#define NOUTC 512

__device__ inline unsigned short f2bf(float f) {
  union { float f; unsigned u; } c; c.f = f;
  unsigned u = c.u;
  return (unsigned short)((u + 0x7FFFu + ((u >> 16) & 1u)) >> 16);  // RNE
}
__device__ inline float bf2f(unsigned short h) {
  union { unsigned u; float f; } c; c.u = ((unsigned)h) << 16;
  return c.f;
}

// W1t[j][k] = bf16(W1'[k][j]); W1'[k][j] = j<256 ? W1[k][j] : W1[256+k][j-256]
__global__ void w1t_kernel(const float* __restrict__ W1, unsigned short* __restrict__ W1t) {
  int t = blockIdx.x * 256 + threadIdx.x;           // 0..131071
  int j = t >> 8, k = t & 255;
  float v = W1[(size_t)(k + ((j >= 256) ? 256 : 0)) * DINC + (j & 255)];
  W1t[(size_t)j * DINC + k] = f2bf(v);
}

// Block: 256 thr = 4 waves in 2x2; per-wave 64x64 output; block tile 128x128.
// Grid: m_tiles * (512/128). No LDS: A frags from fp32 x (cvt in reg), B frags
// from bf16 W1t (L2-resident, 256 KB).
__global__ __launch_bounds__(256) void uv_gemm(const float* __restrict__ x,
                                               const unsigned short* __restrict__ W1t,
                                               unsigned short* __restrict__ uv,
                                               int Nn, int m_tiles) {
  int bm = blockIdx.x % m_tiles;       // m fastest -> A streams within XCD, W1t L2-resident
  int bn = blockIdx.x / m_tiles;       // 0..3
  int lane = threadIdx.x & 63;
  int wid  = threadIdx.x >> 6;         // 0..3
  int wm = wid >> 1, wn = wid & 1;
  int m0 = bm * 128 + wm * 64;
  int n0 = bn * 128 + wn * 64;
  int lr = lane & 15;                  // fragment row/col
  int kg = lane >> 4;                  // k-group: lane holds k = 8*kg .. 8*kg+7

  f32x4 acc[4][4] = {};

#pragma unroll 2
  for (int k0 = 0; k0 < DINC; k0 += 32) {
    short8 a[4], b[4];
#pragma unroll
    for (int mf = 0; mf < 4; ++mf) {
      int row = m0 + mf * 16 + lr;
      row = row < Nn ? row : Nn - 1;   // clamp OOB reads (stores guarded below)
      const float4* ap = (const float4*)(x + (size_t)row * DINC + k0 + kg * 8);
      float4 f0 = ap[0], f1 = ap[1];
      short8 av;
      av[0] = (short)f2bf(f0.x); av[1] = (short)f2bf(f0.y);
      av[2] = (short)f2bf(f0.z); av[3] = (short)f2bf(f0.w);
      av[4] = (short)f2bf(f1.x); av[5] = (short)f2bf(f1.y);
      av[6] = (short)f2bf(f1.z); av[7] = (short)f2bf(f1.w);
      a[mf] = av;
    }
#pragma unroll
    for (int nf = 0; nf < 4; ++nf) {
      int col = n0 + nf * 16 + lr;
      b[nf] = *(const short8*)(W1t + (size_t)col * DINC + k0 + kg * 8);
    }
#pragma unroll
    for (int mf = 0; mf < 4; ++mf)
#pragma unroll
      for (int nf = 0; nf < 4; ++nf)
        acc[mf][nf] = __builtin_amdgcn_mfma_f32_16x16x32_bf16(a[mf], b[nf], acc[mf][nf], 0, 0, 0);
  }

  // C/D layout (measured, guide §3): col = lane&15, row = (lane>>4)*4 + reg
#pragma unroll
  for (int mf = 0; mf < 4; ++mf) {
#pragma unroll
    for (int nf = 0; nf < 4; ++nf) {
      int colg = n0 + nf * 16 + lr;
#pragma unroll
      for (int r = 0; r < 4; ++r) {
        int rowg = m0 + mf * 16 + kg * 4 + r;
        if (rowg < Nn) uv[(size_t)rowg * NOUTC + colg] = f2bf(acc[mf][nf][r]);
      }
    }
  }
}

// One wave per edge; lane owns 4 of 256 channels; shuffle-reduce the dot.
__global__ __launch_bounds__(512) void edge_kernel(const int* __restrict__ eliW,
                                                   const unsigned short* __restrict__ uv,
                                                   const float* __restrict__ b1,
                                                   const float* __restrict__ W2,
                                                   const float* __restrict__ b2,
                                                   float* __restrict__ out, int E) {
  int lane = threadIdx.x & 63;
  // Detect int64 vs int32 index storage: int64 little-endian puts zero high
  // words at odd int32 positions (values < 2^31).
  bool is64 = ((eliW[1] | eliW[3] | eliW[5] | eliW[7] | eliW[9] | eliW[11]) == 0);
  int shift = is64 ? 1 : 0;

  float4 b1s = *(const float4*)(b1 + lane * 4);
  float4 w2s = *(const float4*)(W2 + lane * 4);
  float bias2 = b2[0];

  int wgid = blockIdx.x * (blockDim.x >> 6) + (threadIdx.x >> 6);
  int nw = gridDim.x * (blockDim.x >> 6);

  for (int e = wgid; e < E; e += nw) {
    int src = eliW[((size_t)e) << shift];
    int dst = eliW[((size_t)(E + e)) << shift];
    ushort4 u4 = *(const ushort4*)(uv + (size_t)src * NOUTC + lane * 4);
    ushort4 v4 = *(const ushort4*)(uv + (size_t)dst * NOUTC + DINC + lane * 4);
    float s = 0.f, h;
    h = bf2f(u4.x) + bf2f(v4.x) + b1s.x; s += fmaxf(h, 0.f) * w2s.x;
    h = bf2f(u4.y) + bf2f(v4.y) + b1s.y; s += fmaxf(h, 0.f) * w2s.y;
    h = bf2f(u4.z) + bf2f(v4.z) + b1s.z; s += fmaxf(h, 0.f) * w2s.z;
    h = bf2f(u4.w) + bf2f(v4.w) + b1s.w; s += fmaxf(h, 0.f) * w2s.w;
#pragma unroll
    for (int off = 32; off; off >>= 1) s += __shfl_xor(s, off, 64);
    if (lane == 0) out[e] = s + bias2;
  }
}

extern "C" void kernel_launch(void* const* d_in, const int* in_sizes, int n_in,
                              void* d_out, int out_size, void* d_ws, size_t ws_size,
                              hipStream_t stream) {
  const float* x  = (const float*)d_in[0];
  const int*   eli = (const int*)d_in[1];
  const float* W1 = (const float*)d_in[2];
  const float* b1 = (const float*)d_in[3];
  const float* W2 = (const float*)d_in[4];
  const float* b2 = (const float*)d_in[5];
  float* out = (float*)d_out;

  int Nn = in_sizes[0] / DINC;     // 100000
  int E  = in_sizes[1] / 2;        // 500000

  unsigned short* W1t = (unsigned short*)d_ws;              // 512*256*2 = 256 KB
  unsigned short* uv  = W1t + (size_t)NOUTC * DINC;         // Nn*512*2 ~ 102.4 MB

  w1t_kernel<<<512, 256, 0, stream>>>(W1, W1t);

  int m_tiles = (Nn + 127) / 128;
  uv_gemm<<<m_tiles * (NOUTC / 128), 256, 0, stream>>>(x, W1t, uv, Nn, m_tiles);

  edge_kernel<<<2048, 512, 0, stream>>>(eli, uv, b1, W2, b2, out, E);
}

// Round 2
// 194.494 us; speedup vs baseline: 1.2222x; 1.2222x over previous
//
#include <hip/hip_runtime.h>
#include <hip/hip_bf16.h>

// out[e] = relu(concat(x[src],x[dst]) @ W1 + b1) @ W2 + b2
// Phase 1: uv[n][0:256] = x[n]@W1[0:256], uv[n][256:512] = x[n]@W1[256:512] (bf16)
// Phase 2: per-edge sum_k relu(uv[src][k]+uv[dst][256+k]+b1[k])*W2[k] + b2.

typedef short short8 __attribute__((ext_vector_type(8)));
typedef float f32x4 __attribute__((ext_vector_type(4)));

#define DINC 256
#define NOUTC 512

__device__ inline unsigned short f2bf(float f) {
  union { float f; unsigned u; } c; c.f = f;
  unsigned u = c.u;
  return (unsigned short)((u + 0x7FFFu + ((u >> 16) & 1u)) >> 16);  // RNE
}
__device__ inline float bf2f(unsigned short h) {
  union { unsigned u; float f; } c; c.u = ((unsigned)h) << 16;
  return c.f;
}

// W1t[j][k] = bf16(W1'[k][j]); W1'[k][j] = j<256 ? W1[k][j] : W1[256+k][j-256]
__global__ void w1t_kernel(const float* __restrict__ W1, unsigned short* __restrict__ W1t) {
  int t = blockIdx.x * 256 + threadIdx.x;           // 0..131071
  int j = t >> 8, k = t & 255;
  float v = W1[(size_t)(k + ((j >= 256) ? 256 : 0)) * DINC + (j & 255)];
  W1t[(size_t)j * DINC + k] = f2bf(v);
}

// 256 thr = 4 waves (2x2), block tile 128x128, BK=64, K=256 -> 4 k-tiles.
// A: global fp32 -> reg -> cvt bf16 -> XOR-swizzled LDS (double buffered).
// Swizzle: 16B chunk index within a 128B row: phys_chunk = log_chunk ^ (row&7).
// B: direct per-lane 16B loads from L2-resident W1t.
__global__ __launch_bounds__(256) void uv_gemm(const float* __restrict__ x,
                                               const unsigned short* __restrict__ W1t,
                                               unsigned short* __restrict__ uv,
                                               int Nn, int m_tiles) {
  __shared__ unsigned short As[2][128 * 64];   // 2 x 16 KB

  // XCD-bijective chunked swizzle (m204): logical tiles bn-fastest so the 4
  // bn-tiles sharing one A-row-panel run on the same XCD (A L2-reuse x4).
  int nwg = gridDim.x;
  int q = nwg >> 3, r = nwg & 7;
  int xcd = blockIdx.x & 7, rank = blockIdx.x >> 3;
  int L = (xcd < r) ? (xcd * (q + 1) + rank) : (r * (q + 1) + (xcd - r) * q + rank);
  int bm = L >> 2, bn = L & 3;

  int tid = threadIdx.x, lane = tid & 63, wid = tid >> 6;
  int wm = wid >> 1, wn = wid & 1;
  int m0 = bm * 128 + wm * 64;
  int n0 = bn * 128 + wn * 64;
  int lr = lane & 15;            // fragment row/col within 16
  int kg = lane >> 4;            // k-group (8 elems each)

  // staging coords: thread -> (row, half-row of 32 floats)
  int srow = tid >> 1, shalf = tid & 1;
  int grow = bm * 128 + srow;
  if (grow >= Nn) grow = Nn - 1;                    // clamp (stores guarded)
  const float* gbase = x + (size_t)grow * DINC + shalf * 32;
  int swrow = (srow & 7);

  f32x4 acc[4][4] = {};
  float4 ar[8];
#pragma unroll
  for (int j = 0; j < 8; ++j) ar[j] = ((const float4*)gbase)[j];   // kt=0

  for (int kt = 0; kt < 4; ++kt) {
    // ---- cvt + swizzled ds_write (consumes ar) ----
    char* lbase = (char*)&As[kt & 1][0] + srow * 128;
#pragma unroll
    for (int j = 0; j < 4; ++j) {
      float4 f0 = ar[2 * j], f1 = ar[2 * j + 1];
      short8 v;
      v[0] = (short)f2bf(f0.x); v[1] = (short)f2bf(f0.y);
      v[2] = (short)f2bf(f0.z); v[3] = (short)f2bf(f0.w);
      v[4] = (short)f2bf(f1.x); v[5] = (short)f2bf(f1.y);
      v[6] = (short)f2bf(f1.z); v[7] = (short)f2bf(f1.w);
      int chunk = (shalf * 4 + j) ^ swrow;          // 16B-chunk swizzle
      *(short8*)(lbase + chunk * 16) = v;
    }
    __syncthreads();   // ds_writes visible; single barrier per tile (dbuf-safe)

    // ---- B fragments for this k-tile (L2-resident) ----
    short8 bfr[2][4];
#pragma unroll
    for (int ks = 0; ks < 2; ++ks)
#pragma unroll
      for (int nf = 0; nf < 4; ++nf)
        bfr[ks][nf] = *(const short8*)(W1t + (size_t)(n0 + nf * 16 + lr) * DINC +
                                       kt * 64 + ks * 32 + kg * 8);

    // ---- prefetch next A tile into regs (flies under the MFMAs) ----
    if (kt < 3) {
      const float* gnext = gbase + (kt + 1) * 64;
#pragma unroll
      for (int j = 0; j < 8; ++j) ar[j] = ((const float4*)gnext)[j];
    }

    // ---- compute ----
    char* rbase = (char*)&As[kt & 1][0];
#pragma unroll
    for (int ks = 0; ks < 2; ++ks) {
      short8 a[4];
#pragma unroll
      for (int mf = 0; mf < 4; ++mf) {
        int row = wm * 64 + mf * 16 + lr;
        int chunk = (ks * 4 + kg) ^ (lr & 7);       // same involution as write
        a[mf] = *(const short8*)(rbase + row * 128 + chunk * 16);
      }
#pragma unroll
      for (int mf = 0; mf < 4; ++mf)
#pragma unroll
        for (int nf = 0; nf < 4; ++nf)
          acc[mf][nf] = __builtin_amdgcn_mfma_f32_16x16x32_bf16(a[mf], bfr[ks][nf],
                                                                acc[mf][nf], 0, 0, 0);
    }
  }

  // C/D layout: col = lane&15, row = (lane>>4)*4 + reg
#pragma unroll
  for (int mf = 0; mf < 4; ++mf) {
#pragma unroll
    for (int nf = 0; nf < 4; ++nf) {
      int colg = n0 + nf * 16 + lr;
#pragma unroll
      for (int rr = 0; rr < 4; ++rr) {
        int rowg = m0 + mf * 16 + kg * 4 + rr;
        if (rowg < Nn) uv[(size_t)rowg * NOUTC + colg] = f2bf(acc[mf][nf][rr]);
      }
    }
  }
}

// Quarter-wave (16 lanes) per edge: lane owns 16 of 256 channels (two 8-chunks),
// 4 edges in flight per wave, 4-step shuffle reduce.
__global__ __launch_bounds__(256) void edge_kernel(const int* __restrict__ eliW,
                                                   const unsigned short* __restrict__ uv,
                                                   const float* __restrict__ b1,
                                                   const float* __restrict__ W2,
                                                   const float* __restrict__ b2,
                                                   float* __restrict__ out, int E) {
  int tid = threadIdx.x;
  int ql = tid & 15;   // lane within quarter
  // int64 vs int32 index storage sniff (little-endian high words are zero)
  bool is64 = ((eliW[1] | eliW[3] | eliW[5] | eliW[7] | eliW[9] | eliW[11]) == 0);
  int shift = is64 ? 1 : 0;

  float bl[16], wl[16];
  *(float4*)(bl + 0)  = *(const float4*)(b1 + ql * 8);
  *(float4*)(bl + 4)  = *(const float4*)(b1 + ql * 8 + 4);
  *(float4*)(bl + 8)  = *(const float4*)(b1 + 128 + ql * 8);
  *(float4*)(bl + 12) = *(const float4*)(b1 + 128 + ql * 8 + 4);
  *(float4*)(wl + 0)  = *(const float4*)(W2 + ql * 8);
  *(float4*)(wl + 4)  = *(const float4*)(W2 + ql * 8 + 4);
  *(float4*)(wl + 8)  = *(const float4*)(W2 + 128 + ql * 8);
  *(float4*)(wl + 12) = *(const float4*)(W2 + 128 + ql * 8 + 4);
  float bias2 = b2[0];

  int qid = (blockIdx.x * blockDim.x + tid) >> 4;     // global quarter id
  int nq = (gridDim.x * blockDim.x) >> 4;

  for (int e = qid; e < E; e += nq) {
    int src = eliW[((size_t)e) << shift];
    int dst = eliW[((size_t)(E + e)) << shift];
    const unsigned short* up = uv + (size_t)src * NOUTC;
    const unsigned short* vp = uv + (size_t)dst * NOUTC + DINC;
    short8 uu[2], vv[2];
    uu[0] = *(const short8*)(up + ql * 8);
    uu[1] = *(const short8*)(up + 128 + ql * 8);
    vv[0] = *(const short8*)(vp + ql * 8);
    vv[1] = *(const short8*)(vp + 128 + ql * 8);
    float s = 0.f;
#pragma unroll
    for (int g = 0; g < 2; ++g)
#pragma unroll
      for (int j = 0; j < 8; ++j) {
        float h = bf2f((unsigned short)uu[g][j]) + bf2f((unsigned short)vv[g][j]) + bl[g * 8 + j];
        s += fmaxf(h, 0.f) * wl[g * 8 + j];
      }
#pragma unroll
    for (int off = 8; off; off >>= 1) s += __shfl_xor(s, off, 64);
    if (ql == 0) out[e] = s + bias2;
  }
}

extern "C" void kernel_launch(void* const* d_in, const int* in_sizes, int n_in,
                              void* d_out, int out_size, void* d_ws, size_t ws_size,
                              hipStream_t stream) {
  const float* x   = (const float*)d_in[0];
  const int*   eli = (const int*)d_in[1];
  const float* W1  = (const float*)d_in[2];
  const float* b1  = (const float*)d_in[3];
  const float* W2  = (const float*)d_in[4];
  const float* b2  = (const float*)d_in[5];
  float* out = (float*)d_out;

  int Nn = in_sizes[0] / DINC;     // 100000
  int E  = in_sizes[1] / 2;        // 500000

  unsigned short* W1t = (unsigned short*)d_ws;              // 512*256*2 = 256 KB
  unsigned short* uv  = W1t + (size_t)NOUTC * DINC;         // Nn*512*2 ~ 102.4 MB

  w1t_kernel<<<512, 256, 0, stream>>>(W1, W1t);

  int m_tiles = (Nn + 127) / 128;
  uv_gemm<<<m_tiles * (NOUTC / 128), 256, 0, stream>>>(x, W1t, uv, Nn, m_tiles);

  edge_kernel<<<2048, 256, 0, stream>>>(eli, uv, b1, W2, b2, out, E);
}

// Round 3
// 145.407 us; speedup vs baseline: 1.6349x; 1.3376x over previous
//
#include <hip/hip_runtime.h>
#include <hip/hip_bf16.h>

// out[e] = relu(concat(x[src],x[dst]) @ W1 + b1) @ W2 + b2
// Phase 1: uv[n][0:256] = x[n]@W1[:256,:], uv[n][256:512] = x[n]@W1[256:,:]  (bf16)
// Phase 2: per-edge sum_k relu(uv[src][k]+uv[dst][256+k]+b1[k])*W2[k] + b2.

typedef short short8 __attribute__((ext_vector_type(8)));
typedef float f32x4 __attribute__((ext_vector_type(4)));

#define DINC 256
#define NOUTC 512

__device__ inline unsigned short f2bf(float f) {
  union { float f; unsigned u; } c; c.f = f;
  unsigned u = c.u;
  return (unsigned short)((u + 0x7FFFu + ((u >> 16) & 1u)) >> 16);  // RNE
}
__device__ inline float bf2f(unsigned short h) {
  union { unsigned u; float f; } c; c.u = ((unsigned)h) << 16;
  return c.f;
}

// W1t_swz[col][stored]: stored 16B-chunk = (k>>3) ^ (col&7)  (XOR swizzle baked
// into the global layout so global_load_lds' linear LDS write lands pre-swizzled;
// XOR operand <8 keeps every 64-k slice contiguous per col).
__global__ void w1t_kernel(const float* __restrict__ W1, unsigned short* __restrict__ W1t) {
  int t = blockIdx.x * 256 + threadIdx.x;           // 0..131071
  int j = t >> 8, k = t & 255;                      // j = output col (0..511), k = input dim
  float v = W1[(size_t)(k + ((j >= 256) ? 256 : 0)) * DINC + (j & 255)];
  int sk = (((k >> 3) ^ (j & 7)) << 3) | (k & 7);
  W1t[(size_t)j * DINC + sk] = f2bf(v);
}

// 256 thr = 4 waves (2x2), tile 128x128, BK=64, K=256 -> 4 k-tiles.
// A: wave-contiguous fp32 loads -> reg cvt -> XOR-swizzled ds_write_b64 (dbuf).
// B: global_load_lds 16B from pre-swizzled W1t (dbuf), issued one phase ahead.
// MFMA operands swapped -> lane holds 4 consecutive uv cols -> 8B stores.
__global__ __launch_bounds__(256) void uv_gemm(const float* __restrict__ x,
                                               const unsigned short* __restrict__ W1t,
                                               unsigned short* __restrict__ uv,
                                               int Nn, int m_tiles) {
  __shared__ unsigned short As[2][128 * 64];   // 2 x 16 KB
  __shared__ unsigned short Bs[2][128 * 64];   // 2 x 16 KB

  // XCD-bijective swizzle, bn-fastest (4 bn-tiles of one A-panel share an XCD L2)
  int nwg = gridDim.x;
  int q = nwg >> 3, r = nwg & 7;
  int xcd = blockIdx.x & 7, rank = blockIdx.x >> 3;
  int L = (xcd < r) ? (xcd * (q + 1) + rank) : (r * (q + 1) + (xcd - r) * q + rank);
  int bm = L >> 2, bn = L & 3;

  int tid = threadIdx.x, lane = tid & 63, w = tid >> 6;
  int wm = w >> 1, wn = w & 1;
  int lr = lane & 15, kg = lane >> 4;
  int m0 = bm * 128 + wm * 64, n0 = bn * 128 + wn * 64;

  // A staging coords: load j covers flat float4 idx f = j*256+tid;
  // row = j*16 + (tid>>4), c4 = tid&15  -> each instr is 4KB dense.
  int arow = tid >> 4, ac4 = tid & 15;

  f32x4 acc[4][4] = {};
  float4 ar[8];

#define ISSUE_A(KT)                                                            \
  {                                                                            \
    _Pragma("unroll")                                                          \
    for (int j = 0; j < 8; ++j) {                                              \
      int grow = bm * 128 + j * 16 + arow;                                     \
      if (grow >= Nn) grow = Nn - 1;                                           \
      ar[j] = *((const float4*)(x + (size_t)grow * DINC + (KT) * 64) + ac4);   \
    }                                                                          \
  }

#define ISSUE_B(KT, BUF)                                                       \
  {                                                                            \
    _Pragma("unroll")                                                          \
    for (int c = 0; c < 4; ++c) {                                              \
      const unsigned short* src =                                              \
          W1t + (size_t)(bn * 128 + ((c * 256 + tid) >> 3)) * DINC +           \
          (KT) * 64 + (tid & 7) * 8;                                           \
      unsigned short* dst = &Bs[BUF][(c * 256 + w * 64) * 8];                  \
      __builtin_amdgcn_global_load_lds(                                        \
          (const __attribute__((address_space(1))) void*)src,                  \
          (__attribute__((address_space(3))) void*)dst, 16, 0, 0);             \
    }                                                                          \
  }

#define WRITE_A(BUF)                                                           \
  {                                                                            \
    _Pragma("unroll")                                                          \
    for (int j = 0; j < 8; ++j) {                                              \
      int rl = j * 16 + arow;                                                  \
      ushort4 pk;                                                              \
      pk.x = f2bf(ar[j].x); pk.y = f2bf(ar[j].y);                              \
      pk.z = f2bf(ar[j].z); pk.w = f2bf(ar[j].w);                              \
      char* dp = (char*)&As[BUF][0] + rl * 128 +                               \
                 ((((ac4 >> 1) ^ (rl & 7)) << 4) | ((ac4 & 1) << 3));          \
      *(ushort4*)dp = pk;                                                      \
    }                                                                          \
  }

  ISSUE_A(0);
  ISSUE_B(0, 0);
  WRITE_A(0);
  __syncthreads();

  for (int kt = 0; kt < 4; ++kt) {
    int b = kt & 1;
    if (kt < 3) { ISSUE_A(kt + 1); ISSUE_B(kt + 1, b ^ 1); }

#pragma unroll
    for (int ks = 0; ks < 2; ++ks) {
      short8 af[4], bf_[4];
#pragma unroll
      for (int mf = 0; mf < 4; ++mf) {
        int row = wm * 64 + mf * 16 + lr;
        int phys = (ks * 4 + kg) ^ (lr & 7);
        af[mf] = *(const short8*)((char*)&As[b][0] + row * 128 + phys * 16);
      }
#pragma unroll
      for (int nf = 0; nf < 4; ++nf) {
        int col = wn * 64 + nf * 16 + lr;
        int phys = (ks * 4 + kg) ^ (lr & 7);
        bf_[nf] = *(const short8*)((char*)&Bs[b][0] + col * 128 + phys * 16);
      }
#pragma unroll
      for (int mf = 0; mf < 4; ++mf)
#pragma unroll
        for (int nf = 0; nf < 4; ++nf)
          acc[mf][nf] = __builtin_amdgcn_mfma_f32_16x16x32_bf16(bf_[nf], af[mf],
                                                                acc[mf][nf], 0, 0, 0);
    }

    if (kt < 3) { WRITE_A(b ^ 1); }
    __syncthreads();
  }

  // Swapped-operand C/D layout: lane holds row m = m0+mf*16+lr,
  // cols n = n0+nf*16+kg*4 + rr (rr=0..3 consecutive) -> 8B stores.
#pragma unroll
  for (int mf = 0; mf < 4; ++mf) {
    int m = m0 + mf * 16 + lr;
    if (m < Nn) {
      unsigned short* orow = uv + (size_t)m * NOUTC;
#pragma unroll
      for (int nf = 0; nf < 4; ++nf) {
        ushort4 pk;
        pk.x = f2bf(acc[mf][nf][0]);
        pk.y = f2bf(acc[mf][nf][1]);
        pk.z = f2bf(acc[mf][nf][2]);
        pk.w = f2bf(acc[mf][nf][3]);
        *(ushort4*)(orow + n0 + nf * 16 + kg * 4) = pk;
      }
    }
  }
#undef ISSUE_A
#undef ISSUE_B
#undef WRITE_A
}

// Quarter-wave (16 lanes) per edge: lane owns 16 of 256 channels.
__global__ __launch_bounds__(256) void edge_kernel(const int* __restrict__ eliW,
                                                   const unsigned short* __restrict__ uv,
                                                   const float* __restrict__ b1,
                                                   const float* __restrict__ W2,
                                                   const float* __restrict__ b2,
                                                   float* __restrict__ out, int E) {
  int tid = threadIdx.x;
  int ql = tid & 15;
  bool is64 = ((eliW[1] | eliW[3] | eliW[5] | eliW[7] | eliW[9] | eliW[11]) == 0);
  int shift = is64 ? 1 : 0;

  float bl[16], wl[16];
  *(float4*)(bl + 0)  = *(const float4*)(b1 + ql * 8);
  *(float4*)(bl + 4)  = *(const float4*)(b1 + ql * 8 + 4);
  *(float4*)(bl + 8)  = *(const float4*)(b1 + 128 + ql * 8);
  *(float4*)(bl + 12) = *(const float4*)(b1 + 128 + ql * 8 + 4);
  *(float4*)(wl + 0)  = *(const float4*)(W2 + ql * 8);
  *(float4*)(wl + 4)  = *(const float4*)(W2 + ql * 8 + 4);
  *(float4*)(wl + 8)  = *(const float4*)(W2 + 128 + ql * 8);
  *(float4*)(wl + 12) = *(const float4*)(W2 + 128 + ql * 8 + 4);
  float bias2 = b2[0];

  int qid = (blockIdx.x * blockDim.x + tid) >> 4;
  int nq = (gridDim.x * blockDim.x) >> 4;

  for (int e = qid; e < E; e += nq) {
    int src = eliW[((size_t)e) << shift];
    int dst = eliW[((size_t)(E + e)) << shift];
    const unsigned short* up = uv + (size_t)src * NOUTC;
    const unsigned short* vp = uv + (size_t)dst * NOUTC + DINC;
    short8 uu[2], vv[2];
    uu[0] = *(const short8*)(up + ql * 8);
    uu[1] = *(const short8*)(up + 128 + ql * 8);
    vv[0] = *(const short8*)(vp + ql * 8);
    vv[1] = *(const short8*)(vp + 128 + ql * 8);
    float s = 0.f;
#pragma unroll
    for (int g = 0; g < 2; ++g)
#pragma unroll
      for (int j = 0; j < 8; ++j) {
        float h = bf2f((unsigned short)uu[g][j]) + bf2f((unsigned short)vv[g][j]) + bl[g * 8 + j];
        s += fmaxf(h, 0.f) * wl[g * 8 + j];
      }
#pragma unroll
    for (int off = 8; off; off >>= 1) s += __shfl_xor(s, off, 64);
    if (ql == 0) out[e] = s + bias2;
  }
}

extern "C" void kernel_launch(void* const* d_in, const int* in_sizes, int n_in,
                              void* d_out, int out_size, void* d_ws, size_t ws_size,
                              hipStream_t stream) {
  const float* x   = (const float*)d_in[0];
  const int*   eli = (const int*)d_in[1];
  const float* W1  = (const float*)d_in[2];
  const float* b1  = (const float*)d_in[3];
  const float* W2  = (const float*)d_in[4];
  const float* b2  = (const float*)d_in[5];
  float* out = (float*)d_out;

  int Nn = in_sizes[0] / DINC;     // 100000
  int E  = in_sizes[1] / 2;        // 500000

  unsigned short* W1t = (unsigned short*)d_ws;              // 512*256*2 = 256 KB
  unsigned short* uv  = W1t + (size_t)NOUTC * DINC;         // Nn*512*2 ~ 102.4 MB

  w1t_kernel<<<512, 256, 0, stream>>>(W1, W1t);

  int m_tiles = (Nn + 127) / 128;
  uv_gemm<<<m_tiles * (NOUTC / 128), 256, 0, stream>>>(x, W1t, uv, Nn, m_tiles);

  edge_kernel<<<2048, 256, 0, stream>>>(eli, uv, b1, W2, b2, out, E);
}